// Round 7
// baseline (92.410 us; speedup 1.0000x reference)
//
#include <hip/hip_runtime.h>
#include <math.h>

// x: [128,128,128,16] f32 ; MaxPool3d win 4 stride 2 -> pooled [63,63,63,16]
// patches: 30^3 cubes of 4^3 at stride 2 -> out (27000, 64, 16) f32
#define D0 128
#define NC 16
#define DP 63
#define NPATCH 30
#define HWP_THREADS (D0*DP*DP*4)           // stage A: thread per (d, hp, wp, c4)
#define DPOOL_THREADS (DP*DP*DP*4)         // stage B: thread per (dp, hp, wp, c4)
#define OUT_THREADS  (NPATCH*NPATCH*NPATCH*64*4)  // stage C: thread per out float4
// rolling-d fallback (round-4 kernel) params
#define DCH 7
#define NCHUNK 9
#define POOL2_THREADS (NCHUNK*DP*DP*4)

typedef float f32x4 __attribute__((ext_vector_type(4)));  // native vec for NT store

__device__ __forceinline__ float4 f4max(float4 a, float4 b) {
    return make_float4(fmaxf(a.x, b.x), fmaxf(a.y, b.y), fmaxf(a.z, b.z), fmaxf(a.w, b.w));
}

// Stage A: hw-pool. hwp[d][hp][wp][c] = max over 4x4 (h,w) window at depth d.
// 2.03M threads -> 124 waves/CU; x read ~once; store flat float4 idx == tid.
__global__ void hw_pool_kernel(const float* __restrict__ x, float* __restrict__ hwp) {
    const int tid = blockIdx.x * blockDim.x + threadIdx.x;
    if (tid >= HWP_THREADS) return;
    const int c4 = tid & 3;
    int rest = tid >> 2;
    const int wp = rest % DP; rest /= DP;
    const int hp = rest % DP;
    const int d = rest / DP;           // 0..127

    const size_t base = (size_t)d * D0 * D0 + (hp * 2) * D0 + wp * 2;
    float4 m = make_float4(-INFINITY, -INFINITY, -INFINITY, -INFINITY);
#pragma unroll
    for (int v = 0; v < 4; ++v) {
#pragma unroll
        for (int w = 0; w < 4; ++w) {
            const float4 val = *reinterpret_cast<const float4*>(
                &x[(base + v * D0 + w) * NC + c4 * 4]);
            m = f4max(m, val);
        }
    }
    *reinterpret_cast<float4*>(&hwp[(size_t)tid * 4]) = m;
}

// Stage B: d-pool. pooled[dp][hp][wp][c] = max over 4 consecutive hwp slices.
// 1M threads, 4 coalesced float4 loads each; 2x slice re-read is L2-absorbed.
__global__ void d_pool_kernel(const float* __restrict__ hwp, float* __restrict__ pooled) {
    const int tid = blockIdx.x * blockDim.x + threadIdx.x;
    if (tid >= DPOOL_THREADS) return;
    const int c4 = tid & 3;
    int rest = tid >> 2;
    const int wp = rest % DP; rest /= DP;
    const int hp = rest % DP;
    const int dp = rest / DP;          // 0..62

    float4 m = make_float4(-INFINITY, -INFINITY, -INFINITY, -INFINITY);
#pragma unroll
    for (int u = 0; u < 4; ++u) {
        const size_t src = (size_t)((((dp * 2 + u) * DP + hp) * DP + wp) * 4 + c4);
        m = f4max(m, *reinterpret_cast<const float4*>(&hwp[src * 4]));
    }
    *reinterpret_cast<float4*>(&pooled[(size_t)tid * 4]) = m;
}

// Stage C: gather into (27000, 64, 16); out flat float4 idx == tid, NT store.
__global__ void gather_kernel(const float* __restrict__ pooled, float* __restrict__ out) {
    const int stride = gridDim.x * blockDim.x;
    for (int tid = blockIdx.x * blockDim.x + threadIdx.x; tid < OUT_THREADS; tid += stride) {
        const int c4 = tid & 3;
        const int w = (tid >> 2) & 63;     // (a*4+b)*4+cc
        const int n = tid >> 8;            // patch index (i*30+j)*30+k
        const int cc = w & 3;
        const int b = (w >> 2) & 3;
        const int a = w >> 4;
        const int k = n % NPATCH;
        const int t = n / NPATCH;
        const int j = t % NPATCH;
        const int i = t / NPATCH;
        const int dp = i * 2 + a;
        const int hp = j * 2 + b;
        const int wp = k * 2 + cc;
        const int src = ((dp * DP + hp) * DP + wp) * 4 + c4;  // float4 index
        const f32x4 v = *reinterpret_cast<const f32x4*>(&pooled[(size_t)src * 4]);
        __builtin_nontemporal_store(v, reinterpret_cast<f32x4*>(&out[(size_t)tid * 4]));
    }
}

// ---- fallbacks ----
// Rolling-d pool (round-4): used if ws fits only the 16MB pooled buffer.
__global__ void pool_kernel(const float* __restrict__ x, float* __restrict__ pooled) {
    const int tid = blockIdx.x * blockDim.x + threadIdx.x;
    if (tid >= POOL2_THREADS) return;
    const int c4 = tid & 3;
    int rest = tid >> 2;
    const int wp = rest % DP; rest /= DP;
    const int hp = rest % DP;
    const int chunk = rest / DP;
    const int dp0 = chunk * DCH;

    float4 hw[2 * DCH + 2];
    const int hwbase = (hp * 2) * D0 + wp * 2;
#pragma unroll
    for (int ld = 0; ld < 2 * DCH + 2; ++ld) {
        const int d = 2 * dp0 + ld;
        const size_t dbase = (size_t)d * D0 * D0 + hwbase;
        float4 m = make_float4(-INFINITY, -INFINITY, -INFINITY, -INFINITY);
#pragma unroll
        for (int v = 0; v < 4; ++v)
#pragma unroll
            for (int w = 0; w < 4; ++w)
                m = f4max(m, *reinterpret_cast<const float4*>(
                    &x[(dbase + v * D0 + w) * NC + c4 * 4]));
        hw[ld] = m;
    }
#pragma unroll
    for (int i = 0; i < DCH; ++i) {
        const int dp = dp0 + i;
        const float4 r = f4max(f4max(hw[2 * i], hw[2 * i + 1]),
                               f4max(hw[2 * i + 2], hw[2 * i + 3]));
        *reinterpret_cast<float4*>(&pooled[(size_t)(((dp * DP + hp) * DP + wp) * 4 + c4) * 4]) = r;
    }
}

// Full recompute fallback (no workspace).
__global__ void fused_kernel(const float* __restrict__ x, float* __restrict__ out) {
    const int stride = gridDim.x * blockDim.x;
    for (int tid = blockIdx.x * blockDim.x + threadIdx.x; tid < OUT_THREADS; tid += stride) {
        const int c4 = tid & 3;
        const int w = (tid >> 2) & 63;
        const int n = tid >> 8;
        const int cc = w & 3;
        const int b = (w >> 2) & 3;
        const int a = w >> 4;
        const int k = n % NPATCH;
        const int t = n / NPATCH;
        const int j = t % NPATCH;
        const int i = t / NPATCH;
        const int dp = i * 2 + a;
        const int hp = j * 2 + b;
        const int wp = k * 2 + cc;
        float4 m = make_float4(-INFINITY, -INFINITY, -INFINITY, -INFINITY);
        const int xpos0 = ((dp * 2) * D0 + hp * 2) * D0 + wp * 2;
        for (int u = 0; u < 4; ++u)
            for (int v = 0; v < 4; ++v) {
                const int rowpos = xpos0 + (u * D0 + v) * D0;
#pragma unroll
                for (int ww = 0; ww < 4; ++ww)
                    m = f4max(m, *reinterpret_cast<const float4*>(
                        &x[(size_t)(rowpos + ww) * NC + c4 * 4]));
            }
        *reinterpret_cast<float4*>(&out[(size_t)tid * 4]) = m;
    }
}

extern "C" void kernel_launch(void* const* d_in, const int* in_sizes, int n_in,
                              void* d_out, int out_size, void* d_ws, size_t ws_size,
                              hipStream_t stream) {
    const float* x = (const float*)d_in[0];
    float* out = (float*)d_out;

    const size_t hwp_bytes = (size_t)D0 * DP * DP * NC * sizeof(float);     // 32.5 MB
    const size_t pooled_bytes = (size_t)DP * DP * DP * NC * sizeof(float);  // 16 MB
    const int threads = 256;

    if (ws_size >= hwp_bytes + pooled_bytes) {
        float* hwp = (float*)d_ws;
        float* pooled = (float*)((char*)d_ws + ((hwp_bytes + 255) & ~(size_t)255));

        hw_pool_kernel<<<(HWP_THREADS + threads - 1) / threads, threads, 0, stream>>>(x, hwp);
        d_pool_kernel<<<(DPOOL_THREADS + threads - 1) / threads, threads, 0, stream>>>(hwp, pooled);

        int blocks = (OUT_THREADS + threads - 1) / threads;
        if (blocks > 2048) blocks = 2048;
        gather_kernel<<<blocks, threads, 0, stream>>>(pooled, out);
    } else if (ws_size >= pooled_bytes) {
        float* pooled = (float*)d_ws;
        pool_kernel<<<(POOL2_THREADS + threads - 1) / threads, threads, 0, stream>>>(x, pooled);
        int blocks = (OUT_THREADS + threads - 1) / threads;
        if (blocks > 2048) blocks = 2048;
        gather_kernel<<<blocks, threads, 0, stream>>>(pooled, out);
    } else {
        int blocks = (OUT_THREADS + threads - 1) / threads;
        if (blocks > 2048) blocks = 2048;
        fused_kernel<<<blocks, threads, 0, stream>>>(x, out);
    }
}